// Round 2
// baseline (2937.248 us; speedup 1.0000x reference)
//
#include <hip/hip_runtime.h>
#include <hip/hip_bf16.h>
#include <math.h>

#define NPOS 10000
#define NANCH 30000
#define PRE 2000
#define POST 1000
#define CLAMPD 4.135166556742356

__device__ __forceinline__ unsigned long long mapu64(double f) {
  unsigned long long b = (unsigned long long)__double_as_longlong(f);
  return (b & 0x8000000000000000ULL) ? ~b : (b | 0x8000000000000000ULL);
}

// ---------------- repack conv weights: w[co][ci][k] (f32) -> wT[ci][k][co] (f64) ----------------
__global__ void repack_w_k(const float* __restrict__ w, double* __restrict__ wT) {
  int tid = blockIdx.x * 256 + threadIdx.x;
  if (tid >= 589824) return;
  int co = tid / 2304;
  int rem = tid % 2304;        // ci*9 + k
  wT[rem * 256 + co] = (double)w[tid];
}

// ---------------- features NCHW -> NHWC (featT[b][pos][c], f32) ----------------
__global__ void transpose_feat_k(const float* __restrict__ feat, float* __restrict__ featT) {
  __shared__ float tile[32][33];
  int b = blockIdx.z;
  int c0 = blockIdx.y * 32;
  int p0 = blockIdx.x * 32;
  int tx = threadIdx.x & 31, ty = threadIdx.x >> 5;  // 8 rows
  for (int r = 0; r < 4; ++r) {
    int c = c0 + ty + r * 8, p = p0 + tx;
    tile[ty + r * 8][tx] = (p < NPOS) ? feat[((size_t)b * 256 + c) * NPOS + p] : 0.f;
  }
  __syncthreads();
  for (int r = 0; r < 4; ++r) {
    int p = p0 + ty + r * 8, c = c0 + tx;
    if (p < NPOS) featT[((size_t)b * NPOS + p) * 256 + c] = tile[tx][ty + r * 8];
  }
}

// ---------------- 3x3 conv (SAME) + bias + relu, FP64 ----------------
// block: 64 spatial (8x8 tile) x 64 co; 256 threads; thread = 4 spatial x 4 co
__global__ void conv3x3_relu_k(const float* __restrict__ feat, const double* __restrict__ wT,
                               const float* __restrict__ bias, double* __restrict__ t) {
  __shared__ double it[10][12];
  __shared__ double ws[9][64];
  int tid = threadIdx.x;
  int tileid = blockIdx.x;
  int ty0 = (tileid / 13) * 8, tx0 = (tileid % 13) * 8;
  int co0 = blockIdx.y * 64;
  int b = blockIdx.z;
  int tx = tid & 15;           // co quad
  int ty = tid >> 4;           // spatial quad
  int py = ty >> 1, px0 = (ty & 1) * 4;
  double acc[4][4] = {};
  const float* fb = feat + (size_t)b * 256 * NPOS;
  for (int ci = 0; ci < 256; ++ci) {
    __syncthreads();
    if (tid < 120) {
      int r = tid / 12, c = tid % 12;
      int gy = ty0 - 1 + r, gx = tx0 - 1 + c;
      float v = 0.f;
      if (c < 10 && gy >= 0 && gy < 100 && gx >= 0 && gx < 100)
        v = fb[ci * NPOS + gy * 100 + gx];
      it[r][c] = (double)v;
    }
    for (int i = tid; i < 576; i += 256) {
      int k = i >> 6, co = i & 63;
      ws[k][co] = wT[(ci * 9 + k) * 256 + co0 + co];
    }
    __syncthreads();
#pragma unroll
    for (int ky = 0; ky < 3; ++ky) {
      double a8[8];
#pragma unroll
      for (int m = 0; m < 8; ++m) a8[m] = it[py + ky][px0 + m];
#pragma unroll
      for (int kx = 0; kx < 3; ++kx) {
        double w0 = ws[ky * 3 + kx][tx * 4 + 0];
        double w1 = ws[ky * 3 + kx][tx * 4 + 1];
        double w2 = ws[ky * 3 + kx][tx * 4 + 2];
        double w3 = ws[ky * 3 + kx][tx * 4 + 3];
#pragma unroll
        for (int q = 0; q < 4; ++q) {
          double av = a8[q + kx];
          acc[q][0] += av * w0;
          acc[q][1] += av * w1;
          acc[q][2] += av * w2;
          acc[q][3] += av * w3;
        }
      }
    }
  }
  int y = ty0 + py;
  if (y < 100) {
#pragma unroll
    for (int q = 0; q < 4; ++q) {
      int x = tx0 + px0 + q;
      if (x >= 100) continue;
      int pos = y * 100 + x;
#pragma unroll
      for (int j = 0; j < 4; ++j) {
        int co = co0 + tx * 4 + j;
        t[((size_t)b * 256 + co) * NPOS + pos] = fmax(acc[q][j] + (double)bias[co], 0.0);
      }
    }
  }
}

// ---------------- 1x1 heads (FP64): obj (3) + deltas (12) ----------------
__global__ void rpn_heads_k(const double* __restrict__ t, const float* __restrict__ wcls,
                            const float* __restrict__ bcls, const float* __restrict__ wbbox,
                            const float* __restrict__ bbbox, double* __restrict__ obj,
                            double* __restrict__ deltas) {
  __shared__ double wl[256][16];
  int tid = threadIdx.x;
  for (int i = tid; i < 256 * 16; i += 256) {
    int ci = i >> 4, j = i & 15;
    double v = 0.0;
    if (j < 3) v = (double)wcls[j * 256 + ci];
    else if (j < 15) v = (double)wbbox[(j - 3) * 256 + ci];
    wl[ci][j] = v;
  }
  __syncthreads();
  int b = blockIdx.y;
  int pos = blockIdx.x * 256 + tid;
  if (pos >= NPOS) return;
  double acc[15] = {};
  const double* tb = t + (size_t)b * 256 * NPOS + pos;
  for (int ci = 0; ci < 256; ++ci) {
    double v = tb[(size_t)ci * NPOS];
#pragma unroll
    for (int j = 0; j < 15; ++j) acc[j] += v * wl[ci][j];
  }
#pragma unroll
  for (int a = 0; a < 3; ++a)
    obj[(size_t)b * NANCH + pos * 3 + a] = acc[a] + (double)bcls[a];
#pragma unroll
  for (int a = 0; a < 3; ++a)
#pragma unroll
    for (int k = 0; k < 4; ++k)
      deltas[((size_t)b * NANCH + pos * 3 + a) * 4 + k] = acc[3 + a * 4 + k] + (double)bbbox[a * 4 + k];
}

// ---------------- top-2000 select (FP64 keys, exact jax tie semantics) + sort + decode ----------------
__global__ __launch_bounds__(1024) void topk_decode_k(const double* __restrict__ obj,
                                                      const double* __restrict__ deltas,
                                                      double* __restrict__ boxesd,
                                                      float* __restrict__ boxesf) {
  int b = blockIdx.x;
  __shared__ unsigned hist[16][256];
  __shared__ unsigned long long selk[2048];
  __shared__ unsigned seli[2048];
  __shared__ unsigned bitmap[944];
  __shared__ unsigned wpre[1024];
  __shared__ unsigned long long sh_prefix;
  __shared__ unsigned sh_rem, sh_cnt;
  int tid = threadIdx.x;
  int wid = tid >> 6;
  const double* ob = obj + (size_t)b * NANCH;

  if (tid == 0) { sh_prefix = 0ULL; sh_rem = PRE; }
  // 64-bit radix-select: find key T = value of the 2000th-largest
  for (int shift = 56; shift >= 0; shift -= 8) {
    for (int i = tid; i < 16 * 256; i += 1024) ((unsigned*)hist)[i] = 0;
    __syncthreads();
    unsigned long long pref = sh_prefix;
    unsigned long long himask = (shift == 56) ? 0ULL : (~0ULL << (shift + 8));
    for (int i = tid; i < NANCH; i += 1024) {
      unsigned long long u = mapu64(ob[i]);
      if ((u & himask) == pref) atomicAdd(&hist[wid][(unsigned)(u >> shift) & 255u], 1u);
    }
    __syncthreads();
    if (tid < 256) {
      unsigned s = hist[0][tid];
      for (int w = 1; w < 16; ++w) s += hist[w][tid];
      hist[0][tid] = s;
    }
    __syncthreads();
    if (tid == 0) {
      unsigned rem = sh_rem;
      unsigned long long pfx = sh_prefix;
      for (int bb = 255; bb >= 0; --bb) {
        unsigned c = hist[0][bb];
        if (rem > c) rem -= c;
        else { pfx |= ((unsigned long long)bb) << shift; break; }
      }
      sh_prefix = pfx; sh_rem = rem;
    }
    __syncthreads();
  }
  unsigned long long T = sh_prefix;
  unsigned rem = sh_rem;  // how many key==T entries to take (smallest indices first)
  if (tid == 0) sh_cnt = 0;
  for (int i = tid; i < 944; i += 1024) bitmap[i] = 0;
  __syncthreads();
  for (int i = tid; i < NANCH; i += 1024) {
    unsigned long long u = mapu64(ob[i]);
    if (u > T) {
      unsigned p = atomicAdd(&sh_cnt, 1u);
      selk[p] = u; seli[p] = (unsigned)i;
    } else if (u == T) {
      atomicOr(&bitmap[i >> 5], 1u << (i & 31));
    }
  }
  __syncthreads();
  unsigned cntgt = sh_cnt;
  // rank the equal-set by index (inclusive scan of popcounts)
  unsigned pc = (tid < 938) ? __popc(bitmap[tid]) : 0;
  wpre[tid] = pc;
  __syncthreads();
  for (int offs = 1; offs < 1024; offs <<= 1) {
    unsigned v = (tid >= offs) ? wpre[tid - offs] : 0;
    __syncthreads();
    wpre[tid] += v;
    __syncthreads();
  }
  if (tid < 938) {
    unsigned word = bitmap[tid];
    unsigned base = wpre[tid] - __popc(word);
    while (word && base < rem) {
      int bit = __builtin_ctz(word);
      word &= word - 1;
      unsigned p = cntgt + base;
      selk[p] = T;
      seli[p] = (unsigned)(tid * 32 + bit);
      ++base;
    }
  }
  if (tid < 48) { selk[2000 + tid] = 0ULL; seli[2000 + tid] = 0xFFFFFFFFu; }
  __syncthreads();
  // bitonic sort 2048: key desc, idx asc (matches jax top_k tie order)
  for (unsigned k = 2; k <= 2048; k <<= 1) {
    for (unsigned j = k >> 1; j > 0; j >>= 1) {
      for (int i = tid; i < 2048; i += 1024) {
        int l = i ^ (int)j;
        if (l > i) {
          unsigned long long ka = selk[i], kb = selk[l];
          unsigned ia = seli[i], ib = seli[l];
          bool before_lb = (kb > ka) || (kb == ka && ib < ia);
          bool asc = ((i & (int)k) == 0);
          if (asc == before_lb) {
            selk[i] = kb; selk[l] = ka;
            seli[i] = ib; seli[l] = ia;
          }
        }
      }
      __syncthreads();
    }
  }
  // decode + clip, FP64 (anchors built exactly like numpy: f64 -> f32 cast -> promote)
  const double ratios[3] = {0.5, 1.0, 2.0};
  for (int p = tid; p < PRE; p += 1024) {
    unsigned idx = seli[p];
    int a = (int)(idx % 3u);
    int pos = (int)(idx / 3u);
    int ypix = pos / 100, xpix = pos % 100;
    double sx = (double)(xpix * 8), sy = (double)(ypix * 8);
    double sq = sqrt(ratios[a]);
    double w2 = (64.0 / sq) * 0.5;   // w/2 (f64, like numpy)
    double h2 = (64.0 * sq) * 0.5;   // h/2
    float x1a = (float)(sx - w2), y1a = (float)(sy - h2);
    float x2a = (float)(sx + w2), y2a = (float)(sy + h2);
    double wa = (double)x2a - (double)x1a;
    double ha = (double)y2a - (double)y1a;
    double cxa = (double)x1a + 0.5 * wa, cya = (double)y1a + 0.5 * ha;
    const double* dd = deltas + ((size_t)b * NANCH + idx) * 4;
    double dx = dd[0], dy = dd[1];
    double dw = fmin(dd[2], CLAMPD), dh = fmin(dd[3], CLAMPD);
    double cx = dx * wa + cxa, cy = dy * ha + cya;
    double w = exp(dw) * wa, h = exp(dh) * ha;
    double bx1 = fmin(fmax(cx - 0.5 * w, 0.0), 800.0);
    double by1 = fmin(fmax(cy - 0.5 * h, 0.0), 800.0);
    double bx2 = fmin(fmax(cx + 0.5 * w, 0.0), 800.0);
    double by2 = fmin(fmax(cy + 0.5 * h, 0.0), 800.0);
    double* bo = boxesd + ((size_t)b * PRE + p) * 4;
    bo[0] = bx1; bo[1] = by1; bo[2] = bx2; bo[3] = by2;
    float* bf = boxesf + ((size_t)b * PRE + p) * 4;
    bf[0] = (float)bx1; bf[1] = (float)by1; bf[2] = (float)bx2; bf[3] = (float)by2;
  }
}

// ---------------- suppression matrix (FP64 IoU): bit j of row i = (iou>0.7 && j>i) ----------------
__global__ void supmat_k(const double* __restrict__ boxes, unsigned* __restrict__ sup) {
  int b = blockIdx.y;
  int gt = blockIdx.x * 256 + threadIdx.x;
  int i = gt >> 6, w = gt & 63;
  if (i >= PRE) return;
  const double* bb = boxes + (size_t)b * PRE * 4;
  double x1 = bb[i * 4 + 0], y1 = bb[i * 4 + 1], x2 = bb[i * 4 + 2], y2 = bb[i * 4 + 3];
  double a1 = (x2 - x1) * (y2 - y1);
  unsigned m = 0;
  int j0 = w * 32;
  for (int jj = 0; jj < 32; ++jj) {
    int j = j0 + jj;
    if (j >= PRE) break;
    if (j > i) {
      double u1 = bb[j * 4 + 0], v1 = bb[j * 4 + 1], u2 = bb[j * 4 + 2], v2 = bb[j * 4 + 3];
      double ltx = fmax(x1, u1), lty = fmax(y1, v1);
      double rbx = fmin(x2, u2), rby = fmin(y2, v2);
      double ww = fmax(rbx - ltx, 0.0), hh = fmax(rby - lty, 0.0);
      double inter = ww * hh;
      double a2 = (u2 - u1) * (v2 - v1);
      double iou = inter / (a1 + a2 - inter + 1e-9);
      if (iou > 0.7) m |= 1u << jj;
    }
  }
  sup[((size_t)b * 2048 + i) * 64 + w] = m;
}

// ---------------- sequential NMS (wave-lockstep) + emit 1000 rois (f32) ----------------
__global__ void nms_emit_k(const unsigned* __restrict__ sup, const float* __restrict__ boxes,
                           float* __restrict__ rois) {
  int b = blockIdx.x;
  int tid = threadIdx.x;
  __shared__ unsigned buf[64 * 64];
  __shared__ unsigned aw[64];
  __shared__ unsigned pre[64];
  __shared__ unsigned sh_m;
  const unsigned* sb = sup + (size_t)b * 2048 * 64;
  unsigned alive = 0;
  if (tid < 64) alive = (tid < 62) ? 0xFFFFFFFFu : (tid == 62 ? 0xFFFFu : 0u);
  for (int c = 0; c < 32; ++c) {
    __syncthreads();
    for (int idx = tid; idx < 4096; idx += 256) buf[idx] = sb[(size_t)c * 4096 + idx];
    __syncthreads();
    if (tid < 64) {
      for (int ii = 0; ii < 64; ++ii) {
        int i = c * 64 + ii;
        if (i >= PRE) break;
        unsigned av = __shfl(alive, i >> 5);
        if ((av >> (i & 31)) & 1u) alive &= ~buf[ii * 64 + tid];
      }
    }
  }
  if (tid < 64) aw[tid] = alive;
  __syncthreads();
  if (tid == 0) {
    unsigned m = 0;
    for (int w = 0; w < 64; ++w) { pre[w] = m; m += __popc(aw[w]); }
    sh_m = m;
  }
  __syncthreads();
  unsigned m = sh_m;
  for (int i = tid; i < PRE; i += 256) {
    int w = i >> 5;
    unsigned word = aw[w];
    unsigned lower = word & ((1u << (i & 31)) - 1u);
    unsigned rank = pre[w] + __popc(lower);
    bool al = (word >> (i & 31)) & 1u;
    unsigned dst;
    if (al) {
      if (rank >= POST) continue;
      dst = rank;
    } else {
      unsigned dpos = m + ((unsigned)i - rank);  // dead boxes fill by ascending index
      if (dpos >= POST) continue;
      dst = dpos;
    }
    const float4 v = *(const float4*)(boxes + ((size_t)b * PRE + i) * 4);
    *(float4*)(rois + ((size_t)b * POST + dst) * 4) = v;
  }
}

// ---------------- roi align (7x7, SR=2) over NHWC features (f32) ----------------
__global__ void roi_align_k(const float* __restrict__ featT, const float* __restrict__ rois,
                            float* __restrict__ pooled, int b) {
  __shared__ float slx[14], sly[14];
  __shared__ int sx0[14], sx1[14], sy0[14], sy1[14];
  int tid = threadIdx.x;
  int roi = blockIdx.x;
  const float* r = rois + ((size_t)b * POST + roi) * 4;
  if (tid < 14) {
    float x1 = r[0] * 0.125f, x2 = r[2] * 0.125f;
    float bw = (x2 - x1) / 7.0f;
    float k = ((float)tid + 0.5f) / 2.0f;
    float xs = fminf(fmaxf(x1 + bw * k, 0.f), 99.f);
    float x0f = floorf(xs);
    int x0i = (int)x0f;
    sx0[tid] = x0i; sx1[tid] = min(x0i + 1, 99); slx[tid] = xs - x0f;
  } else if (tid < 28) {
    int s = tid - 14;
    float y1 = r[1] * 0.125f, y2 = r[3] * 0.125f;
    float bh = (y2 - y1) / 7.0f;
    float k = ((float)s + 0.5f) / 2.0f;
    float ys = fminf(fmaxf(y1 + bh * k, 0.f), 99.f);
    float y0f = floorf(ys);
    int y0i = (int)y0f;
    sy0[s] = y0i; sy1[s] = min(y0i + 1, 99); sly[s] = ys - y0f;
  }
  __syncthreads();
  int c = tid;
  const float* fb = featT + (size_t)b * NPOS * 256 + c;
  float* outp = pooled + (size_t)roi * 12544 + (size_t)c * 49;
  for (int ph = 0; ph < 7; ++ph) {
    for (int pw = 0; pw < 7; ++pw) {
      float acc = 0.f;
#pragma unroll
      for (int sy = 0; sy < 2; ++sy) {
        int yi = ph * 2 + sy;
        int y0 = sy0[yi], y1 = sy1[yi];
        float ly = sly[yi], hy = 1.f - ly;
#pragma unroll
        for (int sx = 0; sx < 2; ++sx) {
          int xi = pw * 2 + sx;
          int x0 = sx0[xi], x1 = sx1[xi];
          float lx = slx[xi], hx = 1.f - lx;
          float v00 = fb[(size_t)(y0 * 100 + x0) * 256];
          float v01 = fb[(size_t)(y0 * 100 + x1) * 256];
          float v10 = fb[(size_t)(y1 * 100 + x0) * 256];
          float v11 = fb[(size_t)(y1 * 100 + x1) * 256];
          acc += hy * hx * v00 + hy * lx * v01 + ly * hx * v10 + ly * lx * v11;
        }
      }
      outp[ph * 7 + pw] = acc * 0.25f;
    }
  }
}

// ---------------- fp32 GEMM: C = act(A[MxK] @ B[KxN] + bias), 64x64 tile ----------------
__global__ void gemm_f32_k(const float* __restrict__ A, const float* __restrict__ B,
                           const float* __restrict__ bias, float* __restrict__ C,
                           int M, int N, int K, int relu) {
  __shared__ float As[16][68];
  __shared__ float Bs[16][68];
  int tid = threadIdx.x;
  int m0 = blockIdx.y * 64, n0 = blockIdx.x * 64;
  int tx = tid & 15, ty = tid >> 4;
  int la_m = tid >> 2;
  int la_k = (tid & 3) << 2;
  int lb_k = tid >> 4;
  int lb_n = (tid & 15) << 2;
  float acc[4][4] = {};
  for (int k0 = 0; k0 < K; k0 += 16) {
    float4 av;
    if (m0 + la_m < M) av = *(const float4*)(A + (size_t)(m0 + la_m) * K + k0 + la_k);
    else av = make_float4(0.f, 0.f, 0.f, 0.f);
    float4 bv = *(const float4*)(B + (size_t)(k0 + lb_k) * N + n0 + lb_n);
    __syncthreads();
    As[la_k + 0][la_m] = av.x;
    As[la_k + 1][la_m] = av.y;
    As[la_k + 2][la_m] = av.z;
    As[la_k + 3][la_m] = av.w;
    *(float4*)&Bs[lb_k][lb_n] = bv;
    __syncthreads();
#pragma unroll
    for (int kk = 0; kk < 16; ++kk) {
      float4 a4 = *(const float4*)&As[kk][ty * 4];
      float4 b4 = *(const float4*)&Bs[kk][tx * 4];
      float aa[4] = {a4.x, a4.y, a4.z, a4.w};
      float bb[4] = {b4.x, b4.y, b4.z, b4.w};
#pragma unroll
      for (int i = 0; i < 4; ++i)
#pragma unroll
        for (int j = 0; j < 4; ++j)
          acc[i][j] += aa[i] * bb[j];
    }
  }
#pragma unroll
  for (int i = 0; i < 4; ++i) {
    int m = m0 + ty * 4 + i;
    if (m >= M) continue;
    float4 r;
    r.x = acc[i][0] + bias[n0 + tx * 4 + 0];
    r.y = acc[i][1] + bias[n0 + tx * 4 + 1];
    r.z = acc[i][2] + bias[n0 + tx * 4 + 2];
    r.w = acc[i][3] + bias[n0 + tx * 4 + 3];
    if (relu) {
      r.x = fmaxf(r.x, 0.f); r.y = fmaxf(r.y, 0.f);
      r.z = fmaxf(r.z, 0.f); r.w = fmaxf(r.w, 0.f);
    }
    *(float4*)(C + (size_t)m * N + n0 + tx * 4) = r;
  }
}

// ---------------- final heads: out = [x2@cls_w + cls_b, x2@reg_w + reg_b] ----------------
__global__ void final_heads_k(const float* __restrict__ x2, const float* __restrict__ cls_w,
                              const float* __restrict__ cls_b, const float* __restrict__ reg_w,
                              const float* __restrict__ reg_b, float* __restrict__ out, int b) {
  __shared__ float wl[1024][10];
  int tid = threadIdx.x;
  for (int i = tid; i < 1024 * 10; i += 256) {
    int k = i / 10, n = i % 10;
    wl[k][n] = (n < 2) ? cls_w[k * 2 + n] : reg_w[k * 8 + (n - 2)];
  }
  __syncthreads();
  int gt = blockIdx.x * 256 + tid;
  if (gt >= POST * 10) return;
  int m = gt / 10, n = gt % 10;
  const float* xr = x2 + (size_t)m * 1024;
  float acc = 0.f;
  for (int k = 0; k < 1024; ++k) acc += xr[k] * wl[k][n];
  acc += (n < 2) ? cls_b[n] : reg_b[n - 2];
  out[((size_t)b * POST + m) * 10 + n] = acc;
}

extern "C" void kernel_launch(void* const* d_in, const int* in_sizes, int n_in,
                              void* d_out, int out_size, void* d_ws, size_t ws_size,
                              hipStream_t stream) {
  const float* features   = (const float*)d_in[0];
  const float* rpn_conv_w = (const float*)d_in[1];
  const float* rpn_conv_b = (const float*)d_in[2];
  const float* rpn_cls_w  = (const float*)d_in[3];
  const float* rpn_cls_b  = (const float*)d_in[4];
  const float* rpn_bbox_w = (const float*)d_in[5];
  const float* rpn_bbox_b = (const float*)d_in[6];
  const float* fc1_w = (const float*)d_in[7];
  const float* fc1_b = (const float*)d_in[8];
  const float* fc2_w = (const float*)d_in[9];
  const float* fc2_b = (const float*)d_in[10];
  const float* cls_w = (const float*)d_in[11];
  const float* cls_b = (const float*)d_in[12];
  const float* reg_w = (const float*)d_in[13];
  const float* reg_b = (const float*)d_in[14];
  float* out = (float*)d_out;

  char* ws = (char*)d_ws;
  size_t off = 0;
  auto alloc = [&](size_t bytes) -> void* {
    off = (off + 255) & ~(size_t)255;
    void* p = ws + off;
    off += bytes;
    return p;
  };
  // persistent-through-tail buffers first
  float* featT = (float*)alloc((size_t)2 * NPOS * 256 * 4);   // 20.48 MB
  float* rois  = (float*)alloc((size_t)2 * POST * 4 * 4);     // 32 KB
  // RPN region (dead after nms_emit) — pooled aliases this region
  off = (off + 255) & ~(size_t)255;
  size_t region = off;
  double*   wTd    = (double*)alloc((size_t)589824 * 8);          // 4.72 MB
  double*   t      = (double*)alloc((size_t)2 * 256 * NPOS * 8);  // 40.96 MB
  double*   obj    = (double*)alloc((size_t)2 * NANCH * 8);       // 0.48 MB
  double*   deltas = (double*)alloc((size_t)2 * NANCH * 4 * 8);   // 1.92 MB
  double*   boxesd = (double*)alloc((size_t)2 * PRE * 4 * 8);     // 128 KB
  float*    boxesf = (float*)alloc((size_t)2 * PRE * 4 * 4);      // 64 KB
  unsigned* sup    = (unsigned*)alloc((size_t)2 * 2048 * 64 * 4); // 1.05 MB
  alloc((size_t)1 << 20);                                         // pad so region >= pooled
  float* x1b = (float*)alloc((size_t)POST * 1024 * 4);
  float* x2b = (float*)alloc((size_t)POST * 1024 * 4);
  float* pooled = (float*)(ws + region);  // 50.18 MB alias over [wTd..pad]
  (void)ws_size; (void)in_sizes; (void)n_in; (void)out_size;

  repack_w_k<<<(589824 + 255) / 256, 256, 0, stream>>>(rpn_conv_w, wTd);
  transpose_feat_k<<<dim3(313, 8, 2), 256, 0, stream>>>(features, featT);
  conv3x3_relu_k<<<dim3(169, 4, 2), 256, 0, stream>>>(features, wTd, rpn_conv_b, t);
  rpn_heads_k<<<dim3(40, 2), 256, 0, stream>>>(t, rpn_cls_w, rpn_cls_b, rpn_bbox_w, rpn_bbox_b,
                                               obj, deltas);
  topk_decode_k<<<2, 1024, 0, stream>>>(obj, deltas, boxesd, boxesf);
  supmat_k<<<dim3(512, 2), 256, 0, stream>>>(boxesd, sup);
  nms_emit_k<<<2, 256, 0, stream>>>(sup, boxesf, rois);
  for (int b = 0; b < 2; ++b) {
    roi_align_k<<<POST, 256, 0, stream>>>(featT, rois, pooled, b);
    gemm_f32_k<<<dim3(16, 16), 256, 0, stream>>>(pooled, fc1_w, fc1_b, x1b, POST, 1024, 12544, 1);
    gemm_f32_k<<<dim3(16, 16), 256, 0, stream>>>(x1b, fc2_w, fc2_b, x2b, POST, 1024, 1024, 1);
    final_heads_k<<<40, 256, 0, stream>>>(x2b, cls_w, cls_b, reg_w, reg_b, out, b);
  }
}

// Round 3
// 1644.379 us; speedup vs baseline: 1.7862x; 1.7862x over previous
//
#include <hip/hip_runtime.h>
#include <hip/hip_bf16.h>
#include <math.h>

#define NPOS 10000
#define NANCH 30000
#define PRE 2000
#define POST 1000
#define CLAMPD 4.135166556742356

typedef __attribute__((ext_vector_type(8))) short bf16x8v;
typedef __attribute__((ext_vector_type(4))) float f32x4v;

__device__ __forceinline__ unsigned long long mapu64(double f) {
  unsigned long long b = (unsigned long long)__double_as_longlong(f);
  return (b & 0x8000000000000000ULL) ? ~b : (b | 0x8000000000000000ULL);
}

__device__ __forceinline__ void async_load16(const void* g, void* l) {
  __builtin_amdgcn_global_load_lds((const __attribute__((address_space(1))) void*)g,
                                   (__attribute__((address_space(3))) void*)l, 16, 0, 0);
}

// ---------------- repack conv weights: w[co][ci][k] (f32) -> wT[ci][k][co] (f64) ----------------
__global__ void repack_w_k(const float* __restrict__ w, double* __restrict__ wT) {
  int tid = blockIdx.x * 256 + threadIdx.x;
  if (tid >= 589824) return;
  int co = tid / 2304;
  int rem = tid % 2304;        // ci*9 + k
  wT[rem * 256 + co] = (double)w[tid];
}

// ---------------- features NCHW -> NHWC (featT[b][pos][c], f32) ----------------
__global__ void transpose_feat_k(const float* __restrict__ feat, float* __restrict__ featT) {
  __shared__ float tile[32][33];
  int b = blockIdx.z;
  int c0 = blockIdx.y * 32;
  int p0 = blockIdx.x * 32;
  int tx = threadIdx.x & 31, ty = threadIdx.x >> 5;  // 8 rows
  for (int r = 0; r < 4; ++r) {
    int c = c0 + ty + r * 8, p = p0 + tx;
    tile[ty + r * 8][tx] = (p < NPOS) ? feat[((size_t)b * 256 + c) * NPOS + p] : 0.f;
  }
  __syncthreads();
  for (int r = 0; r < 4; ++r) {
    int p = p0 + ty + r * 8, c = c0 + tx;
    if (p < NPOS) featT[((size_t)b * NPOS + p) * 256 + c] = tile[tx][ty + r * 8];
  }
}

// ---------------- weight transpose+convert: w f32[K][N] -> wt bf16[N][K] ----------------
__global__ void wt_bf16_k(const float* __restrict__ w, __hip_bfloat16* __restrict__ wt,
                          int K, int N) {
  __shared__ float tile[32][33];
  int k0 = blockIdx.x * 32, n0 = blockIdx.y * 32;
  int tx = threadIdx.x & 31, ty = threadIdx.x >> 5;  // 8 rows
  for (int r = 0; r < 4; ++r)
    tile[ty + r * 8][tx] = w[(size_t)(k0 + ty + r * 8) * N + n0 + tx];
  __syncthreads();
  for (int r = 0; r < 4; ++r)
    wt[(size_t)(n0 + ty + r * 8) * K + k0 + tx] = __float2bfloat16(tile[tx][ty + r * 8]);
}

// ---------------- 3x3 conv (SAME) + bias + relu, FP64 ----------------
__global__ void conv3x3_relu_k(const float* __restrict__ feat, const double* __restrict__ wT,
                               const float* __restrict__ bias, double* __restrict__ t) {
  __shared__ double it[10][12];
  __shared__ double ws[9][64];
  int tid = threadIdx.x;
  int tileid = blockIdx.x;
  int ty0 = (tileid / 13) * 8, tx0 = (tileid % 13) * 8;
  int co0 = blockIdx.y * 64;
  int b = blockIdx.z;
  int tx = tid & 15;           // co quad
  int ty = tid >> 4;           // spatial quad
  int py = ty >> 1, px0 = (ty & 1) * 4;
  double acc[4][4] = {};
  const float* fb = feat + (size_t)b * 256 * NPOS;
  for (int ci = 0; ci < 256; ++ci) {
    __syncthreads();
    if (tid < 120) {
      int r = tid / 12, c = tid % 12;
      int gy = ty0 - 1 + r, gx = tx0 - 1 + c;
      float v = 0.f;
      if (c < 10 && gy >= 0 && gy < 100 && gx >= 0 && gx < 100)
        v = fb[ci * NPOS + gy * 100 + gx];
      it[r][c] = (double)v;
    }
    for (int i = tid; i < 576; i += 256) {
      int k = i >> 6, co = i & 63;
      ws[k][co] = wT[(ci * 9 + k) * 256 + co0 + co];
    }
    __syncthreads();
#pragma unroll
    for (int ky = 0; ky < 3; ++ky) {
      double a8[8];
#pragma unroll
      for (int m = 0; m < 8; ++m) a8[m] = it[py + ky][px0 + m];
#pragma unroll
      for (int kx = 0; kx < 3; ++kx) {
        double w0 = ws[ky * 3 + kx][tx * 4 + 0];
        double w1 = ws[ky * 3 + kx][tx * 4 + 1];
        double w2 = ws[ky * 3 + kx][tx * 4 + 2];
        double w3 = ws[ky * 3 + kx][tx * 4 + 3];
#pragma unroll
        for (int q = 0; q < 4; ++q) {
          double av = a8[q + kx];
          acc[q][0] += av * w0;
          acc[q][1] += av * w1;
          acc[q][2] += av * w2;
          acc[q][3] += av * w3;
        }
      }
    }
  }
  int y = ty0 + py;
  if (y < 100) {
#pragma unroll
    for (int q = 0; q < 4; ++q) {
      int x = tx0 + px0 + q;
      if (x >= 100) continue;
      int pos = y * 100 + x;
#pragma unroll
      for (int j = 0; j < 4; ++j) {
        int co = co0 + tx * 4 + j;
        t[((size_t)b * 256 + co) * NPOS + pos] = fmax(acc[q][j] + (double)bias[co], 0.0);
      }
    }
  }
}

// ---------------- 1x1 heads (FP64): obj (3) + deltas (12) ----------------
__global__ void rpn_heads_k(const double* __restrict__ t, const float* __restrict__ wcls,
                            const float* __restrict__ bcls, const float* __restrict__ wbbox,
                            const float* __restrict__ bbbox, double* __restrict__ obj,
                            double* __restrict__ deltas) {
  __shared__ double wl[256][16];
  int tid = threadIdx.x;
  for (int i = tid; i < 256 * 16; i += 256) {
    int ci = i >> 4, j = i & 15;
    double v = 0.0;
    if (j < 3) v = (double)wcls[j * 256 + ci];
    else if (j < 15) v = (double)wbbox[(j - 3) * 256 + ci];
    wl[ci][j] = v;
  }
  __syncthreads();
  int b = blockIdx.y;
  int pos = blockIdx.x * 256 + tid;
  if (pos >= NPOS) return;
  double acc[15] = {};
  const double* tb = t + (size_t)b * 256 * NPOS + pos;
  for (int ci = 0; ci < 256; ++ci) {
    double v = tb[(size_t)ci * NPOS];
#pragma unroll
    for (int j = 0; j < 15; ++j) acc[j] += v * wl[ci][j];
  }
#pragma unroll
  for (int a = 0; a < 3; ++a)
    obj[(size_t)b * NANCH + pos * 3 + a] = acc[a] + (double)bcls[a];
#pragma unroll
  for (int a = 0; a < 3; ++a)
#pragma unroll
    for (int k = 0; k < 4; ++k)
      deltas[((size_t)b * NANCH + pos * 3 + a) * 4 + k] = acc[3 + a * 4 + k] + (double)bbbox[a * 4 + k];
}

// ---------------- top-2000 select (FP64 keys, exact jax tie semantics) + sort + decode ----------------
__global__ __launch_bounds__(1024) void topk_decode_k(const double* __restrict__ obj,
                                                      const double* __restrict__ deltas,
                                                      double* __restrict__ boxesd,
                                                      float* __restrict__ boxesf) {
  int b = blockIdx.x;
  __shared__ unsigned hist[16][256];
  __shared__ unsigned long long selk[2048];
  __shared__ unsigned seli[2048];
  __shared__ unsigned bitmap[944];
  __shared__ unsigned wpre[1024];
  __shared__ unsigned long long sh_prefix;
  __shared__ unsigned sh_rem, sh_cnt;
  int tid = threadIdx.x;
  int wid = tid >> 6;
  const double* ob = obj + (size_t)b * NANCH;

  if (tid == 0) { sh_prefix = 0ULL; sh_rem = PRE; }
  for (int shift = 56; shift >= 0; shift -= 8) {
    for (int i = tid; i < 16 * 256; i += 1024) ((unsigned*)hist)[i] = 0;
    __syncthreads();
    unsigned long long pref = sh_prefix;
    unsigned long long himask = (shift == 56) ? 0ULL : (~0ULL << (shift + 8));
    for (int i = tid; i < NANCH; i += 1024) {
      unsigned long long u = mapu64(ob[i]);
      if ((u & himask) == pref) atomicAdd(&hist[wid][(unsigned)(u >> shift) & 255u], 1u);
    }
    __syncthreads();
    if (tid < 256) {
      unsigned s = hist[0][tid];
      for (int w = 1; w < 16; ++w) s += hist[w][tid];
      hist[0][tid] = s;
    }
    __syncthreads();
    if (tid == 0) {
      unsigned rem = sh_rem;
      unsigned long long pfx = sh_prefix;
      for (int bb = 255; bb >= 0; --bb) {
        unsigned c = hist[0][bb];
        if (rem > c) rem -= c;
        else { pfx |= ((unsigned long long)bb) << shift; break; }
      }
      sh_prefix = pfx; sh_rem = rem;
    }
    __syncthreads();
  }
  unsigned long long T = sh_prefix;
  unsigned rem = sh_rem;
  if (tid == 0) sh_cnt = 0;
  for (int i = tid; i < 944; i += 1024) bitmap[i] = 0;
  __syncthreads();
  for (int i = tid; i < NANCH; i += 1024) {
    unsigned long long u = mapu64(ob[i]);
    if (u > T) {
      unsigned p = atomicAdd(&sh_cnt, 1u);
      selk[p] = u; seli[p] = (unsigned)i;
    } else if (u == T) {
      atomicOr(&bitmap[i >> 5], 1u << (i & 31));
    }
  }
  __syncthreads();
  unsigned cntgt = sh_cnt;
  unsigned pc = (tid < 938) ? __popc(bitmap[tid]) : 0;
  wpre[tid] = pc;
  __syncthreads();
  for (int offs = 1; offs < 1024; offs <<= 1) {
    unsigned v = (tid >= offs) ? wpre[tid - offs] : 0;
    __syncthreads();
    wpre[tid] += v;
    __syncthreads();
  }
  if (tid < 938) {
    unsigned word = bitmap[tid];
    unsigned base = wpre[tid] - __popc(word);
    while (word && base < rem) {
      int bit = __builtin_ctz(word);
      word &= word - 1;
      unsigned p = cntgt + base;
      selk[p] = T;
      seli[p] = (unsigned)(tid * 32 + bit);
      ++base;
    }
  }
  if (tid < 48) { selk[2000 + tid] = 0ULL; seli[2000 + tid] = 0xFFFFFFFFu; }
  __syncthreads();
  for (unsigned k = 2; k <= 2048; k <<= 1) {
    for (unsigned j = k >> 1; j > 0; j >>= 1) {
      for (int i = tid; i < 2048; i += 1024) {
        int l = i ^ (int)j;
        if (l > i) {
          unsigned long long ka = selk[i], kb = selk[l];
          unsigned ia = seli[i], ib = seli[l];
          bool before_lb = (kb > ka) || (kb == ka && ib < ia);
          bool asc = ((i & (int)k) == 0);
          if (asc == before_lb) {
            selk[i] = kb; selk[l] = ka;
            seli[i] = ib; seli[l] = ia;
          }
        }
      }
      __syncthreads();
    }
  }
  const double ratios[3] = {0.5, 1.0, 2.0};
  for (int p = tid; p < PRE; p += 1024) {
    unsigned idx = seli[p];
    int a = (int)(idx % 3u);
    int pos = (int)(idx / 3u);
    int ypix = pos / 100, xpix = pos % 100;
    double sx = (double)(xpix * 8), sy = (double)(ypix * 8);
    double sq = sqrt(ratios[a]);
    double w2 = (64.0 / sq) * 0.5;
    double h2 = (64.0 * sq) * 0.5;
    float x1a = (float)(sx - w2), y1a = (float)(sy - h2);
    float x2a = (float)(sx + w2), y2a = (float)(sy + h2);
    double wa = (double)x2a - (double)x1a;
    double ha = (double)y2a - (double)y1a;
    double cxa = (double)x1a + 0.5 * wa, cya = (double)y1a + 0.5 * ha;
    const double* dd = deltas + ((size_t)b * NANCH + idx) * 4;
    double dx = dd[0], dy = dd[1];
    double dw = fmin(dd[2], CLAMPD), dh = fmin(dd[3], CLAMPD);
    double cx = dx * wa + cxa, cy = dy * ha + cya;
    double w = exp(dw) * wa, h = exp(dh) * ha;
    double bx1 = fmin(fmax(cx - 0.5 * w, 0.0), 800.0);
    double by1 = fmin(fmax(cy - 0.5 * h, 0.0), 800.0);
    double bx2 = fmin(fmax(cx + 0.5 * w, 0.0), 800.0);
    double by2 = fmin(fmax(cy + 0.5 * h, 0.0), 800.0);
    double* bo = boxesd + ((size_t)b * PRE + p) * 4;
    bo[0] = bx1; bo[1] = by1; bo[2] = bx2; bo[3] = by2;
    float* bf = boxesf + ((size_t)b * PRE + p) * 4;
    bf[0] = (float)bx1; bf[1] = (float)by1; bf[2] = (float)bx2; bf[3] = (float)by2;
  }
}

// ---------------- suppression matrix (FP64 IoU) ----------------
__global__ void supmat_k(const double* __restrict__ boxes, unsigned* __restrict__ sup) {
  int b = blockIdx.y;
  int gt = blockIdx.x * 256 + threadIdx.x;
  int i = gt >> 6, w = gt & 63;
  if (i >= PRE) return;
  const double* bb = boxes + (size_t)b * PRE * 4;
  double x1 = bb[i * 4 + 0], y1 = bb[i * 4 + 1], x2 = bb[i * 4 + 2], y2 = bb[i * 4 + 3];
  double a1 = (x2 - x1) * (y2 - y1);
  unsigned m = 0;
  int j0 = w * 32;
  for (int jj = 0; jj < 32; ++jj) {
    int j = j0 + jj;
    if (j >= PRE) break;
    if (j > i) {
      double u1 = bb[j * 4 + 0], v1 = bb[j * 4 + 1], u2 = bb[j * 4 + 2], v2 = bb[j * 4 + 3];
      double ltx = fmax(x1, u1), lty = fmax(y1, v1);
      double rbx = fmin(x2, u2), rby = fmin(y2, v2);
      double ww = fmax(rbx - ltx, 0.0), hh = fmax(rby - lty, 0.0);
      double inter = ww * hh;
      double a2 = (u2 - u1) * (v2 - v1);
      double iou = inter / (a1 + a2 - inter + 1e-9);
      if (iou > 0.7) m |= 1u << jj;
    }
  }
  sup[((size_t)b * 2048 + i) * 64 + w] = m;
}

// ---------------- sequential NMS + emit 1000 rois (f32) ----------------
__global__ void nms_emit_k(const unsigned* __restrict__ sup, const float* __restrict__ boxes,
                           float* __restrict__ rois) {
  int b = blockIdx.x;
  int tid = threadIdx.x;
  __shared__ unsigned buf[64 * 64];
  __shared__ unsigned aw[64];
  __shared__ unsigned pre[64];
  __shared__ unsigned sh_m;
  const unsigned* sb = sup + (size_t)b * 2048 * 64;
  unsigned alive = 0;
  if (tid < 64) alive = (tid < 62) ? 0xFFFFFFFFu : (tid == 62 ? 0xFFFFu : 0u);
  for (int c = 0; c < 32; ++c) {
    __syncthreads();
    for (int idx = tid; idx < 4096; idx += 256) buf[idx] = sb[(size_t)c * 4096 + idx];
    __syncthreads();
    if (tid < 64) {
      for (int ii = 0; ii < 64; ++ii) {
        int i = c * 64 + ii;
        if (i >= PRE) break;
        unsigned av = __shfl(alive, i >> 5);
        if ((av >> (i & 31)) & 1u) alive &= ~buf[ii * 64 + tid];
      }
    }
  }
  if (tid < 64) aw[tid] = alive;
  __syncthreads();
  if (tid == 0) {
    unsigned m = 0;
    for (int w = 0; w < 64; ++w) { pre[w] = m; m += __popc(aw[w]); }
    sh_m = m;
  }
  __syncthreads();
  unsigned m = sh_m;
  for (int i = tid; i < PRE; i += 256) {
    int w = i >> 5;
    unsigned word = aw[w];
    unsigned lower = word & ((1u << (i & 31)) - 1u);
    unsigned rank = pre[w] + __popc(lower);
    bool al = (word >> (i & 31)) & 1u;
    unsigned dst;
    if (al) {
      if (rank >= POST) continue;
      dst = rank;
    } else {
      unsigned dpos = m + ((unsigned)i - rank);
      if (dpos >= POST) continue;
      dst = dpos;
    }
    const float4 v = *(const float4*)(boxes + ((size_t)b * PRE + i) * 4);
    *(float4*)(rois + ((size_t)b * POST + dst) * 4) = v;
  }
}

// ---------------- roi align (7x7, SR=2) over NHWC f32 features -> bf16 pooled ----------------
__global__ void roi_align_k(const float* __restrict__ featT, const float* __restrict__ rois,
                            __hip_bfloat16* __restrict__ pooled) {
  __shared__ float slx[14], sly[14];
  __shared__ int sx0[14], sx1[14], sy0[14], sy1[14];
  int tid = threadIdx.x;
  int gro = blockIdx.x;       // 0..1999
  int b = gro / POST;
  const float* r = rois + (size_t)gro * 4;
  if (tid < 14) {
    float x1 = r[0] * 0.125f, x2 = r[2] * 0.125f;
    float bw = (x2 - x1) / 7.0f;
    float k = ((float)tid + 0.5f) / 2.0f;
    float xs = fminf(fmaxf(x1 + bw * k, 0.f), 99.f);
    float x0f = floorf(xs);
    int x0i = (int)x0f;
    sx0[tid] = x0i; sx1[tid] = min(x0i + 1, 99); slx[tid] = xs - x0f;
  } else if (tid < 28) {
    int s = tid - 14;
    float y1 = r[1] * 0.125f, y2 = r[3] * 0.125f;
    float bh = (y2 - y1) / 7.0f;
    float k = ((float)s + 0.5f) / 2.0f;
    float ys = fminf(fmaxf(y1 + bh * k, 0.f), 99.f);
    float y0f = floorf(ys);
    int y0i = (int)y0f;
    sy0[s] = y0i; sy1[s] = min(y0i + 1, 99); sly[s] = ys - y0f;
  }
  __syncthreads();
  int c = tid;
  const float* fb = featT + (size_t)b * NPOS * 256 + c;
  __hip_bfloat16* outp = pooled + (size_t)gro * 12544 + (size_t)c * 49;
  for (int ph = 0; ph < 7; ++ph) {
    for (int pw = 0; pw < 7; ++pw) {
      float acc = 0.f;
#pragma unroll
      for (int sy = 0; sy < 2; ++sy) {
        int yi = ph * 2 + sy;
        int y0 = sy0[yi], y1 = sy1[yi];
        float ly = sly[yi], hy = 1.f - ly;
#pragma unroll
        for (int sx = 0; sx < 2; ++sx) {
          int xi = pw * 2 + sx;
          int x0 = sx0[xi], x1 = sx1[xi];
          float lx = slx[xi], hx = 1.f - lx;
          float v00 = fb[(size_t)(y0 * 100 + x0) * 256];
          float v01 = fb[(size_t)(y0 * 100 + x1) * 256];
          float v10 = fb[(size_t)(y1 * 100 + x0) * 256];
          float v11 = fb[(size_t)(y1 * 100 + x1) * 256];
          acc += hy * hx * v00 + hy * lx * v01 + ly * hx * v10 + ly * lx * v11;
        }
      }
      outp[ph * 7 + pw] = __float2bfloat16(acc * 0.25f);
    }
  }
}

// ---------------- bf16 MFMA GEMM: C = act(A[2048][K] @ Bt[N][K]^T + bias) -> bf16 ----------------
// 128x128 tile, BK=64, 4 waves (each 64x64), global_load_lds(16B), XOR-swizzled LDS
__global__ __launch_bounds__(256) void gemm_bf16_k(const __hip_bfloat16* __restrict__ A,
                                                   const __hip_bfloat16* __restrict__ Bt,
                                                   const float* __restrict__ bias,
                                                   __hip_bfloat16* __restrict__ C,
                                                   int N, int K, int relu) {
  __shared__ __hip_bfloat16 As[128 * 64];
  __shared__ __hip_bfloat16 Bs[128 * 64];
  const int t = threadIdx.x;
  const int w = t >> 6;
  const int lane = t & 63;
  const int lr = lane & 15, lg = lane >> 4;
  const int wr = w >> 1, wc = w & 1;
  const int m0 = blockIdx.y * 128, n0 = blockIdx.x * 128;

  f32x4v acc[4][4];
#pragma unroll
  for (int i = 0; i < 4; ++i)
#pragma unroll
    for (int j = 0; j < 4; ++j)
#pragma unroll
      for (int r = 0; r < 4; ++r) acc[i][j][r] = 0.f;

  // per-thread staging source indices (swizzled): chunk c = i*256 + t
  int srow[4], soff[4];
#pragma unroll
  for (int i = 0; i < 4; ++i) {
    int c = i * 256 + t;
    int row = c >> 3, ccd = c & 7;
    srow[i] = row;
    soff[i] = (ccd ^ (row & 7)) * 8;
  }
  // LDS read offsets
  int arow[4], brow[4], sk[2];
#pragma unroll
  for (int ms = 0; ms < 4; ++ms) arow[ms] = (wr * 64 + ms * 16 + lr) * 128;
#pragma unroll
  for (int ns = 0; ns < 4; ++ns) brow[ns] = (wc * 64 + ns * 16 + lr) * 128;
#pragma unroll
  for (int kk = 0; kk < 2; ++kk) sk[kk] = (((kk * 4 + lg) ^ (lr & 7)) * 16);

  for (int k0 = 0; k0 < K; k0 += 64) {
    __syncthreads();
#pragma unroll
    for (int i = 0; i < 4; ++i) {
      const __hip_bfloat16* ga = A + (size_t)(m0 + srow[i]) * K + k0 + soff[i];
      async_load16(ga, (char*)As + ((i * 256 + w * 64) * 16));
    }
#pragma unroll
    for (int i = 0; i < 4; ++i) {
      const __hip_bfloat16* gb = Bt + (size_t)(n0 + srow[i]) * K + k0 + soff[i];
      async_load16(gb, (char*)Bs + ((i * 256 + w * 64) * 16));
    }
    __syncthreads();

    bf16x8v af[2][4], bf[2][4];
#pragma unroll
    for (int kk = 0; kk < 2; ++kk) {
#pragma unroll
      for (int ms = 0; ms < 4; ++ms)
        af[kk][ms] = *(const bf16x8v*)((const char*)As + arow[ms] + sk[kk]);
#pragma unroll
      for (int ns = 0; ns < 4; ++ns)
        bf[kk][ns] = *(const bf16x8v*)((const char*)Bs + brow[ns] + sk[kk]);
    }
#pragma unroll
    for (int ms = 0; ms < 4; ++ms)
#pragma unroll
      for (int ns = 0; ns < 4; ++ns) {
        acc[ms][ns] = __builtin_amdgcn_mfma_f32_16x16x32_bf16(af[0][ms], bf[0][ns], acc[ms][ns], 0, 0, 0);
        acc[ms][ns] = __builtin_amdgcn_mfma_f32_16x16x32_bf16(af[1][ms], bf[1][ns], acc[ms][ns], 0, 0, 0);
      }
  }

#pragma unroll
  for (int ms = 0; ms < 4; ++ms) {
    int gm = m0 + wr * 64 + ms * 16 + lg * 4;
#pragma unroll
    for (int ns = 0; ns < 4; ++ns) {
      int gn = n0 + wc * 64 + ns * 16 + lr;
      float bv = bias[gn];
#pragma unroll
      for (int r = 0; r < 4; ++r) {
        float v = acc[ms][ns][r] + bv;
        if (relu) v = fmaxf(v, 0.f);
        C[(size_t)(gm + r) * N + gn] = __float2bfloat16(v);
      }
    }
  }
}

// ---------------- final heads: out = [x2@cls_w + cls_b, x2@reg_w + reg_b] ----------------
__global__ void final_heads_k(const __hip_bfloat16* __restrict__ x2,
                              const float* __restrict__ cls_w, const float* __restrict__ cls_b,
                              const float* __restrict__ reg_w, const float* __restrict__ reg_b,
                              float* __restrict__ out) {
  __shared__ float wl[1024][10];
  int tid = threadIdx.x;
  for (int i = tid; i < 1024 * 10; i += 256) {
    int k = i / 10, n = i % 10;
    wl[k][n] = (n < 2) ? cls_w[k * 2 + n] : reg_w[k * 8 + (n - 2)];
  }
  __syncthreads();
  int gt = blockIdx.x * 256 + tid;
  if (gt >= 2 * POST * 10) return;
  int mg = gt / 10, n = gt % 10;
  const __hip_bfloat16* xr = x2 + (size_t)mg * 1024;
  float acc = 0.f;
  for (int k = 0; k < 1024; ++k) acc += __bfloat162float(xr[k]) * wl[k][n];
  acc += (n < 2) ? cls_b[n] : reg_b[n - 2];
  out[(size_t)mg * 10 + n] = acc;
}

extern "C" void kernel_launch(void* const* d_in, const int* in_sizes, int n_in,
                              void* d_out, int out_size, void* d_ws, size_t ws_size,
                              hipStream_t stream) {
  const float* features   = (const float*)d_in[0];
  const float* rpn_conv_w = (const float*)d_in[1];
  const float* rpn_conv_b = (const float*)d_in[2];
  const float* rpn_cls_w  = (const float*)d_in[3];
  const float* rpn_cls_b  = (const float*)d_in[4];
  const float* rpn_bbox_w = (const float*)d_in[5];
  const float* rpn_bbox_b = (const float*)d_in[6];
  const float* fc1_w = (const float*)d_in[7];
  const float* fc1_b = (const float*)d_in[8];
  const float* fc2_w = (const float*)d_in[9];
  const float* fc2_b = (const float*)d_in[10];
  const float* cls_w = (const float*)d_in[11];
  const float* cls_b = (const float*)d_in[12];
  const float* reg_w = (const float*)d_in[13];
  const float* reg_b = (const float*)d_in[14];
  float* out = (float*)d_out;

  char* ws = (char*)d_ws;
  size_t off = 0;
  auto alloc = [&](size_t bytes) -> void* {
    off = (off + 255) & ~(size_t)255;
    void* p = ws + off;
    off += bytes;
    return p;
  };
  // persistent buffers
  float* featT = (float*)alloc((size_t)2 * NPOS * 256 * 4);            // 20.5 MB
  float* rois  = (float*)alloc((size_t)2 * POST * 4 * 4);              // 32 KB
  __hip_bfloat16* w1t = (__hip_bfloat16*)alloc((size_t)1024 * 12544 * 2);  // 25.7 MB
  __hip_bfloat16* w2t = (__hip_bfloat16*)alloc((size_t)1024 * 1024 * 2);   // 2.1 MB
  __hip_bfloat16* x1  = (__hip_bfloat16*)alloc((size_t)2048 * 1024 * 2);   // 4.2 MB
  __hip_bfloat16* x2  = (__hip_bfloat16*)alloc((size_t)2048 * 1024 * 2);   // 4.2 MB
  // aliased region: RPN intermediates, then pooled (dead/alive phases don't overlap)
  off = (off + 255) & ~(size_t)255;
  size_t region = off;
  double*   wTd    = (double*)alloc((size_t)589824 * 8);
  double*   t      = (double*)alloc((size_t)2 * 256 * NPOS * 8);
  double*   obj    = (double*)alloc((size_t)2 * NANCH * 8);
  double*   deltas = (double*)alloc((size_t)2 * NANCH * 4 * 8);
  double*   boxesd = (double*)alloc((size_t)2 * PRE * 4 * 8);
  float*    boxesf = (float*)alloc((size_t)2 * PRE * 4 * 4);
  unsigned* sup    = (unsigned*)alloc((size_t)2 * 2048 * 64 * 4);
  __hip_bfloat16* pooled = (__hip_bfloat16*)(ws + region);  // 2048 x 12544 bf16 = 51.4 MB alias
  size_t pooled_end = region + (size_t)2048 * 12544 * 2;
  if (off < pooled_end) off = pooled_end;
  (void)ws_size; (void)in_sizes; (void)n_in; (void)out_size;

  repack_w_k<<<(589824 + 255) / 256, 256, 0, stream>>>(rpn_conv_w, wTd);
  transpose_feat_k<<<dim3(313, 8, 2), 256, 0, stream>>>(features, featT);
  conv3x3_relu_k<<<dim3(169, 4, 2), 256, 0, stream>>>(features, wTd, rpn_conv_b, t);
  rpn_heads_k<<<dim3(40, 2), 256, 0, stream>>>(t, rpn_cls_w, rpn_cls_b, rpn_bbox_w, rpn_bbox_b,
                                               obj, deltas);
  topk_decode_k<<<2, 1024, 0, stream>>>(obj, deltas, boxesd, boxesf);
  supmat_k<<<dim3(512, 2), 256, 0, stream>>>(boxesd, sup);
  nms_emit_k<<<2, 256, 0, stream>>>(sup, boxesf, rois);
  // FC-path weights to bf16 (transposed) — independent of RPN, any order on stream
  wt_bf16_k<<<dim3(392, 32), 256, 0, stream>>>(fc1_w, w1t, 12544, 1024);
  wt_bf16_k<<<dim3(32, 32), 256, 0, stream>>>(fc2_w, w2t, 1024, 1024);
  // pooled features (both images, bf16)
  roi_align_k<<<2 * POST, 256, 0, stream>>>(featT, rois, pooled);
  // FC1: [2048 x 12544] @ [12544 x 1024] -> x1 ; FC2: -> x2
  gemm_bf16_k<<<dim3(8, 16), 256, 0, stream>>>(pooled, w1t, fc1_b, x1, 1024, 12544, 1);
  gemm_bf16_k<<<dim3(8, 16), 256, 0, stream>>>(x1, w2t, fc2_b, x2, 1024, 1024, 1);
  final_heads_k<<<(2 * POST * 10 + 255) / 256, 256, 0, stream>>>(x2, cls_w, cls_b, reg_w, reg_b, out);
}